// Round 7
// baseline (353.533 us; speedup 1.0000x reference)
//
#include <hip/hip_runtime.h>
#include <hip/hip_fp16.h>

// Problem constants
#define NV   20000
#define KK   3
#define INF  150
#define HH   64
#define OO   128
#define PT   80
#define KTOT 5120      // 80 bins * 64 h
#define XS   168       // x/W1 LDS col stride, halves

typedef _Float16 fh8 __attribute__((ext_vector_type(8)));   // MFMA A/B frag (4 VGPRs)
typedef __attribute__((ext_vector_type(4))) float f32x4;    // MFMA C/D frag

__device__ __forceinline__ unsigned short f2h(float f) {
    return __half_as_ushort(__float2half(f));
}
__device__ __forceinline__ float h2f(unsigned short u) {
    return __half2float(__ushort_as_half(u));
}

// ---------------------------------------------------------------------------
// Fused prep kernel (unchanged — not the bottleneck).
// Blocks 0..127: transpose Wg[o] -> W2 [S][o][kk] fp16 via LDS.
// Blocks 128..752: h = relu(x @ W1^T) -> fp16, 32 rows/block via MFMA.
// ---------------------------------------------------------------------------
__global__ __launch_bounds__(256) void prep_kernel(
    const float* __restrict__ Wg, const float* __restrict__ x,
    const float* __restrict__ W1, unsigned short* __restrict__ W2,
    unsigned short* __restrict__ hb) {
    __shared__ __align__(16) unsigned char smem[32256];
    const int tid = threadIdx.x;

    if (blockIdx.x < 128) {
        float* lds = (float*)smem;                 // 64*81 words
        const int o = blockIdx.x;
        const float* src = Wg + o * KTOT;
        for (int t = tid; t < KTOT; t += 256) {    // t = h*80 + bin
            int h = t / 80, bin = t - h * 80;
            lds[h * 81 + bin] = src[t];
        }
        __syncthreads();
        for (int t = tid; t < KTOT; t += 256) {    // t = k = bin*64 + h
            W2[(t >> 5) * 4096 + o * 32 + (t & 31)] =
                f2h(lds[(t & 63) * 81 + (t >> 6)]);
        }
        return;
    }

    unsigned short* xs = (unsigned short*)smem;    // 32*168
    unsigned short* ws = xs + 32 * XS;             // 64*168
    const int n0 = (blockIdx.x - 128) * 32;

    for (int e = tid; e < 32 * INF; e += 256) {
        int r = e / INF, c = e - r * INF;
        xs[r * XS + c] = f2h(x[n0 * INF + e]);
    }
    for (int e = tid; e < 32 * 18; e += 256) {
        int r = e / 18, c = e - r * 18;
        xs[r * XS + 150 + c] = 0;
    }
    for (int e = tid; e < 64 * INF; e += 256) {
        int r = e / INF, c = e - r * INF;
        ws[r * XS + c] = f2h(W1[e]);
    }
    for (int e = tid; e < 64 * 18; e += 256) {
        int r = e / 18, c = e - r * 18;
        ws[r * XS + 150 + c] = 0;
    }
    __syncthreads();

    const int wv   = tid >> 6;
    const int lane = tid & 63;
    const int q    = lane >> 4;
    const int r16  = lane & 15;
    const int o0   = wv * 16;

    f32x4 acc0 = {0.f, 0.f, 0.f, 0.f};
    f32x4 acc1 = acc0;
    #pragma unroll
    for (int s = 0; s < 5; s++) {
        const int kb = s * 32 + q * 8;
        fh8 a0 = *(const fh8*)(xs + r16 * XS + kb);
        fh8 a1 = *(const fh8*)(xs + (16 + r16) * XS + kb);
        fh8 b  = *(const fh8*)(ws + (o0 + r16) * XS + kb);
        acc0 = __builtin_amdgcn_mfma_f32_16x16x32_f16(a0, b, acc0, 0, 0, 0);
        acc1 = __builtin_amdgcn_mfma_f32_16x16x32_f16(a1, b, acc1, 0, 0, 0);
    }
    #pragma unroll
    for (int r = 0; r < 4; r++) {
        float v0 = acc0[r] > 0.f ? acc0[r] : 0.f;
        float v1 = acc1[r] > 0.f ? acc1[r] : 0.f;
        hb[(n0 + q * 4 + r) * HH + o0 + r16]      = f2h(v0);
        hb[(n0 + 16 + q * 4 + r) * HH + o0 + r16] = f2h(v1);
    }
}

// ---------------------------------------------------------------------------
// Wave-autonomous geo kernel: NO LDS, NO barriers.
// 2500 wave-jobs = 625 blocks x 4 waves. Wave job: 32 vertices (2 m-frags),
// 64 outputs (4 o-tiles), one K-half (40 bins). Per bin:
//   conn (bin+1) prefetch -> regs; 12x16B gathers straight into A-frag lane
//   layout (lane l: vertex l&15, k-chunk l>>4); 8 B-frags from L2-resident
//   W2; fp16 pk-fma combine; 16 MFMA. Compiler handles vmcnt scheduling —
//   no cross-wave convoy. The 4 waves of a block share (oh,ks) so their W2
//   streams alias in L1, but own different vertices (no duplicate gathers).
// Deterministic partials: ks=0 -> fp32 d_out (overwrite), ks=1 -> fp16 part1.
// ---------------------------------------------------------------------------
struct CSet { int i[6]; float w[6]; };   // 2 m-frags x 3 neighbors

__global__ __launch_bounds__(256, 3) void geo_kernel(
    const int*   __restrict__ conn_idx, const float* __restrict__ conn_w,
    const unsigned short* __restrict__ W2, const unsigned short* __restrict__ hb,
    float* __restrict__ out, unsigned short* __restrict__ part1) {
    const int tid  = threadIdx.x;
    const int job  = blockIdx.x * 4 + (tid >> 6);   // 0..2499
    const int lane = tid & 63;
    const int q    = lane >> 4;
    const int r16  = lane & 15;

    const int nblk = job % 625;
    const int rest = job / 625;                     // 0..3
    const int oh   = rest & 1;
    const int ks   = rest >> 1;
    const int n0w  = nblk * 32;
    const int obase = oh * 64;
    const int bbase = ks * 40;

    const int v0 = n0w + r16;
    const int cb0 = v0 * (PT * KK);                 // conn row base, vertex v0
    const int cb1 = cb0 + 16 * (PT * KK);           // vertex v0+16

    f32x4 acc[2][4];
    #pragma unroll
    for (int m = 0; m < 2; m++)
        #pragma unroll
        for (int ot = 0; ot < 4; ot++)
            acc[m][ot] = (f32x4){0.f, 0.f, 0.f, 0.f};

    auto loadc = [&](int bin, CSet& c) {
        const int g0 = cb0 + bin * 3;
        const int g1 = cb1 + bin * 3;
        #pragma unroll
        for (int t = 0; t < 3; t++) {
            c.i[t]     = conn_idx[g0 + t];
            c.w[t]     = conn_w[g0 + t];
            c.i[3 + t] = conn_idx[g1 + t];
            c.w[3 + t] = conn_w[g1 + t];
        }
    };

    auto step = [&](int bin, const CSet& cC, CSet& cN, bool pf) {
        // conn prefetch for bin+1 first (deepest latency)
        if (pf) loadc(bin + 1, cN);
        // gathers: lane l -> 16B of neighbor row, already in A-frag layout
        fh8 hv[12];
        #pragma unroll
        for (int m = 0; m < 2; m++)
            #pragma unroll
            for (int t = 0; t < 3; t++) {
                const unsigned short* p = hb + cC.i[m * 3 + t] * HH + q * 8;
                hv[(m * 3 + t) * 2 + 0] = *(const fh8*)p;
                hv[(m * 3 + t) * 2 + 1] = *(const fh8*)(p + 32);
            }
        // B-frags (coalesced 1KB wave loads from L2-resident W2)
        fh8 Bv[8];
        #pragma unroll
        for (int hf = 0; hf < 2; hf++)
            #pragma unroll
            for (int ot = 0; ot < 4; ot++)
                Bv[hf * 4 + ot] = *(const fh8*)(W2 + (bin * 2 + hf) * 4096 +
                                                (obase + ot * 16 + r16) * 32 + q * 8);
        // combine + MFMA
        #pragma unroll
        for (int m = 0; m < 2; m++) {
            const _Float16 w0 = (_Float16)cC.w[m * 3 + 0];
            const _Float16 w1 = (_Float16)cC.w[m * 3 + 1];
            const _Float16 w2 = (_Float16)cC.w[m * 3 + 2];
            const fh8 W0v = {w0, w0, w0, w0, w0, w0, w0, w0};
            const fh8 W1v = {w1, w1, w1, w1, w1, w1, w1, w1};
            const fh8 W2v = {w2, w2, w2, w2, w2, w2, w2, w2};
            #pragma unroll
            for (int hf = 0; hf < 2; hf++) {
                fh8 A = hv[(m * 3 + 0) * 2 + hf] * W0v +
                        hv[(m * 3 + 1) * 2 + hf] * W1v +
                        hv[(m * 3 + 2) * 2 + hf] * W2v;
                #pragma unroll
                for (int ot = 0; ot < 4; ot++)
                    acc[m][ot] = __builtin_amdgcn_mfma_f32_16x16x32_f16(
                        A, Bv[hf * 4 + ot], acc[m][ot], 0, 0, 0);
            }
        }
    };

    CSet cA, cB;
    loadc(bbase, cA);
    for (int i = 0; i < 40; i += 2) {
        step(bbase + i,     cA, cB, i + 1 < 40);
        step(bbase + i + 1, cB, cA, i + 2 < 40);
    }

    // Partial store. D layout: row = q*4+reg (vertex), col = r16 (o in tile).
    // Exactly one writer per element per stage; pure overwrite.
    if (ks == 0) {
        #pragma unroll
        for (int m = 0; m < 2; m++)
            #pragma unroll
            for (int ot = 0; ot < 4; ot++)
                #pragma unroll
                for (int r = 0; r < 4; r++)
                    out[(n0w + m * 16 + q * 4 + r) * OO + obase + ot * 16 + r16] =
                        acc[m][ot][r];
    } else {
        #pragma unroll
        for (int m = 0; m < 2; m++)
            #pragma unroll
            for (int ot = 0; ot < 4; ot++)
                #pragma unroll
                for (int r = 0; r < 4; r++)
                    part1[(n0w + m * 16 + q * 4 + r) * OO + obase + ot * 16 + r16] =
                        f2h(acc[m][ot][r]);
    }
}

// ---------------------------------------------------------------------------
// Epilogue: v = part0(out) + part1 + bg; out = v * rsqrt(sum v^2) per row.
// 32 rows/block, 8 threads per row. Reads then fully overwrites d_out.
// ---------------------------------------------------------------------------
__global__ __launch_bounds__(256) void norm_kernel(
    float* __restrict__ out, const unsigned short* __restrict__ part1,
    const float* __restrict__ bg) {
    const int tid = threadIdx.x;
    const int n   = blockIdx.x * 32 + (tid >> 3);
    const int l   = tid & 7;
    float v[16];
    float s = 0.f;
    #pragma unroll
    for (int i = 0; i < 16; i++) {
        const int o = i * 8 + l;
        v[i] = out[n * OO + o] + h2f(part1[n * OO + o]) + bg[o];
        s += v[i] * v[i];
    }
    for (int off = 4; off; off >>= 1) s += __shfl_down(s, off, 8);
    const float r = rsqrtf(__shfl(s, 0, 8));
    #pragma unroll
    for (int i = 0; i < 16; i++)
        out[n * OO + i * 8 + l] = v[i] * r;
}

// ---------------------------------------------------------------------------
extern "C" void kernel_launch(void* const* d_in, const int* in_sizes, int n_in,
                              void* d_out, int out_size, void* d_ws, size_t ws_size,
                              hipStream_t stream) {
    const float* x        = (const float*)d_in[0];
    const int*   conn_idx = (const int*)  d_in[1];
    const float* conn_w   = (const float*)d_in[2];
    const float* W1       = (const float*)d_in[3];
    const float* Wg       = (const float*)d_in[4];
    const float* bg       = (const float*)d_in[5];
    float*       out      = (float*)d_out;

    unsigned short* W2    = (unsigned short*)d_ws;         // 655360 fp16 (1.31 MB)
    unsigned short* hb    = W2 + OO * KTOT;                // 1,280,000 fp16 (2.56 MB)
    unsigned short* part1 = hb + NV * HH;                  // 2,560,000 fp16 (5.12 MB)

    hipLaunchKernelGGL(prep_kernel, dim3(128 + NV / 32), dim3(256), 0, stream,
                       Wg, x, W1, W2, hb);
    hipLaunchKernelGGL(geo_kernel, dim3(625), dim3(256), 0, stream,
                       conn_idx, conn_w, W2, hb, out, part1);
    hipLaunchKernelGGL(norm_kernel, dim3(NV / 32), dim3(256), 0, stream,
                       out, part1, bg);
}

// Round 8
// 187.416 us; speedup vs baseline: 1.8864x; 1.8864x over previous
//
#include <hip/hip_runtime.h>
#include <hip/hip_fp16.h>

// Problem constants
#define NV   20000
#define KK   3
#define INF  150
#define HH   64
#define OO   128
#define PT   80
#define KTOT 5120      // 80 bins * 64 h
#define NB   32        // vertices per geo block
#define BS2  72        // per-bin stride in pch, halves (64 + 8 pad)
#define RS2  152       // 2-bin row stride = 2*BS2 + 8 halves (76 words %32 == 12)
#define CHB  (NB * RS2)   // 4864 halves = 9728 B per buffer
#define XS   168       // x/W1 LDS col stride, halves
#define NSUB 10        // sub-chunks per block (20 bins / 2)

typedef _Float16 fh8 __attribute__((ext_vector_type(8)));   // MFMA A/B frag (4 VGPRs)
typedef __attribute__((ext_vector_type(4))) float f32x4;    // MFMA C/D frag

__device__ __forceinline__ unsigned short f2h(float f) {
    return __half_as_ushort(__float2half(f));
}
__device__ __forceinline__ float h2f(unsigned short u) {
    return __half2float(__ushort_as_half(u));
}

struct Conn { int idx[6]; float w[6]; };   // 2 vertex-groups x 3 neighbors

// ---------------------------------------------------------------------------
// Fused prep kernel (unchanged).
// Blocks 0..127: transpose Wg[o] -> W2 [S][o][kk] fp16 via LDS.
// Blocks 128..752: h = relu(x @ W1^T) -> fp16, 32 rows/block via MFMA.
// ---------------------------------------------------------------------------
__global__ __launch_bounds__(256) void prep_kernel(
    const float* __restrict__ Wg, const float* __restrict__ x,
    const float* __restrict__ W1, unsigned short* __restrict__ W2,
    unsigned short* __restrict__ hb) {
    __shared__ __align__(16) unsigned char smem[32256];
    const int tid = threadIdx.x;

    if (blockIdx.x < 128) {
        float* lds = (float*)smem;                 // 64*81 words
        const int o = blockIdx.x;
        const float* src = Wg + o * KTOT;
        for (int t = tid; t < KTOT; t += 256) {    // t = h*80 + bin
            int h = t / 80, bin = t - h * 80;
            lds[h * 81 + bin] = src[t];
        }
        __syncthreads();
        for (int t = tid; t < KTOT; t += 256) {    // t = k = bin*64 + h
            W2[(t >> 5) * 4096 + o * 32 + (t & 31)] =
                f2h(lds[(t & 63) * 81 + (t >> 6)]);
        }
        return;
    }

    unsigned short* xs = (unsigned short*)smem;    // 32*168
    unsigned short* ws = xs + 32 * XS;             // 64*168
    const int n0 = (blockIdx.x - 128) * 32;

    for (int e = tid; e < 32 * INF; e += 256) {
        int r = e / INF, c = e - r * INF;
        xs[r * XS + c] = f2h(x[n0 * INF + e]);
    }
    for (int e = tid; e < 32 * 18; e += 256) {
        int r = e / 18, c = e - r * 18;
        xs[r * XS + 150 + c] = 0;
    }
    for (int e = tid; e < 64 * INF; e += 256) {
        int r = e / INF, c = e - r * INF;
        ws[r * XS + c] = f2h(W1[e]);
    }
    for (int e = tid; e < 64 * 18; e += 256) {
        int r = e / 18, c = e - r * 18;
        ws[r * XS + 150 + c] = 0;
    }
    __syncthreads();

    const int wv   = tid >> 6;
    const int lane = tid & 63;
    const int q    = lane >> 4;
    const int r16  = lane & 15;
    const int o0   = wv * 16;

    f32x4 acc0 = {0.f, 0.f, 0.f, 0.f};
    f32x4 acc1 = acc0;
    #pragma unroll
    for (int s = 0; s < 5; s++) {
        const int kb = s * 32 + q * 8;
        fh8 a0 = *(const fh8*)(xs + r16 * XS + kb);
        fh8 a1 = *(const fh8*)(xs + (16 + r16) * XS + kb);
        fh8 b  = *(const fh8*)(ws + (o0 + r16) * XS + kb);
        acc0 = __builtin_amdgcn_mfma_f32_16x16x32_f16(a0, b, acc0, 0, 0, 0);
        acc1 = __builtin_amdgcn_mfma_f32_16x16x32_f16(a1, b, acc1, 0, 0, 0);
    }
    #pragma unroll
    for (int r = 0; r < 4; r++) {
        float v0 = acc0[r] > 0.f ? acc0[r] : 0.f;
        float v1 = acc1[r] > 0.f ? acc1[r] : 0.f;
        hb[(n0 + q * 4 + r) * HH + o0 + r16]      = f2h(v0);
        hb[(n0 + 16 + q * 4 + r) * HH + o0 + r16] = f2h(v1);
    }
}

// ---------------------------------------------------------------------------
// Split-K x4 geo kernel: grid 2500 = 625 n-blocks x 4 K-slices (20 bins each).
// Round-6 pipeline per sub-chunk (2 bins, 128 k): conn 2 ahead -> regs,
// hb gathers 1 ahead -> regs, 4 MFMA k-steps on current LDS buffer,
// combine+write other buffer, 1 barrier. 10 sub-chunks per block.
// Occupancy: LDS 19.5 KB -> 8 blocks/CU cap; grid 9.8/CU; VGPR ~60.
// Deterministic partials: ks=0 -> fp32 d_out (overwrite), ks>=1 -> fp16
// partsK[ks-1]. No atomics, no memset, no entry-state dependence.
// ---------------------------------------------------------------------------
__global__ __launch_bounds__(256, 4) void geo_kernel(
    const int*   __restrict__ conn_idx, const float* __restrict__ conn_w,
    const unsigned short* __restrict__ W2, const unsigned short* __restrict__ hb,
    float* __restrict__ out, unsigned short* __restrict__ parts) {
    __shared__ __align__(16) unsigned short pch[2 * CHB];  // 19456 B

    const int tid  = threadIdx.x;
    const int ks   = blockIdx.x & 3;             // K-slice 0..3
    const int n0   = (blockIdx.x >> 2) * NB;
    const int wv   = tid >> 6;
    const int lane = tid & 63;
    const int q    = lane >> 4;
    const int r16  = lane & 15;
    const int j8   = tid & 7;                    // 16B segment of h row
    const int bl   = (tid >> 3) & 1;             // bin within sub-chunk
    const int ng   = tid >> 4;                   // vertex sub-row 0..15
    const int bbase = ks * 20;                   // first bin of this K-slice
    const int Sbase = ks * 40;                   // first 32-k step

    f32x4 acc00 = {0.f, 0.f, 0.f, 0.f};
    f32x4 acc01 = acc00, acc10 = acc00, acc11 = acc00;

    Conn cA, cB;
    fh8  hv[6];

    auto loadc = [&](int cc, Conn& c) {          // conn for sub-chunk cc
        const int bin = bbase + cc * 2 + bl;
        #pragma unroll
        for (int i = 0; i < 2; i++) {
            const int g = (n0 + ng + i * 16) * (PT * KK) + bin * KK;
            c.idx[i * 3 + 0] = conn_idx[g];
            c.idx[i * 3 + 1] = conn_idx[g + 1];
            c.idx[i * 3 + 2] = conn_idx[g + 2];
            c.w[i * 3 + 0]   = conn_w[g];
            c.w[i * 3 + 1]   = conn_w[g + 1];
            c.w[i * 3 + 2]   = conn_w[g + 2];
        }
    };
    auto loadh = [&](const Conn& c) {            // gather h rows -> regs
        #pragma unroll
        for (int t = 0; t < 6; t++)
            hv[t] = *(const fh8*)(hb + c.idx[t] * HH + j8 * 8);
    };
    auto cwrite = [&](const Conn& c, unsigned short* buf) {  // combine + LDS
        #pragma unroll
        for (int i = 0; i < 2; i++) {
            const int n = ng + i * 16;
            _Float16 w0 = (_Float16)c.w[i * 3 + 0];
            _Float16 w1 = (_Float16)c.w[i * 3 + 1];
            _Float16 w2 = (_Float16)c.w[i * 3 + 2];
            fh8 W0 = {w0, w0, w0, w0, w0, w0, w0, w0};
            fh8 W1v = {w1, w1, w1, w1, w1, w1, w1, w1};
            fh8 W2v = {w2, w2, w2, w2, w2, w2, w2, w2};
            fh8 r = hv[i * 3] * W0 + hv[i * 3 + 1] * W1v + hv[i * 3 + 2] * W2v;
            *(fh8*)(buf + n * RS2 + bl * BS2 + j8 * 8) = r;
        }
    };
    auto mfmaph = [&](const unsigned short* buf, int cc) {   // 4 k-steps
        #pragma unroll
        for (int s = 0; s < 4; s++) {
            const int S  = Sbase + cc * 4 + s;
            const int ao = (s >> 1) * BS2 + (s & 1) * 32 + q * 8;
            fh8 a0 = *(const fh8*)(buf + r16 * RS2 + ao);
            fh8 a1 = *(const fh8*)(buf + (16 + r16) * RS2 + ao);
            fh8 b0 = *(const fh8*)(W2 + S * 4096 + (wv * 32 + r16) * 32 + q * 8);
            fh8 b1 = *(const fh8*)(W2 + S * 4096 + (wv * 32 + 16 + r16) * 32 + q * 8);
            acc00 = __builtin_amdgcn_mfma_f32_16x16x32_f16(a0, b0, acc00, 0, 0, 0);
            acc01 = __builtin_amdgcn_mfma_f32_16x16x32_f16(a0, b1, acc01, 0, 0, 0);
            acc10 = __builtin_amdgcn_mfma_f32_16x16x32_f16(a1, b0, acc10, 0, 0, 0);
            acc11 = __builtin_amdgcn_mfma_f32_16x16x32_f16(a1, b1, acc11, 0, 0, 0);
        }
    };

    // Prologue
    loadc(0, cA);
    loadc(1, cB);
    loadh(cA);
    cwrite(cA, pch);
    __syncthreads();

    auto body = [&](int cc, Conn& use, Conn& fill) {
        if (cc + 2 < NSUB) loadc(cc + 2, fill);  // conn 2 ahead
        if (cc + 1 < NSUB) loadh(use);           // gathers 1 ahead, in flight
        mfmaph(&pch[(cc & 1) * CHB], cc);        //   across the MFMA phase
        if (cc + 1 < NSUB) cwrite(use, &pch[((cc + 1) & 1) * CHB]);
        __syncthreads();
    };
    for (int cc = 0; cc < NSUB; cc += 2) {
        body(cc, cB, cA);
        body(cc + 1, cA, cB);
    }

    // Partial store. D layout: row = q*4+reg, col = r16. Exactly one writer
    // per element per stage -> deterministic, pure overwrite.
    const int o0 = wv * 32;
    if (ks == 0) {
        #pragma unroll
        for (int r = 0; r < 4; r++) {
            out[(n0 + q * 4 + r) * OO + o0 + r16]           = acc00[r];
            out[(n0 + q * 4 + r) * OO + o0 + 16 + r16]      = acc01[r];
            out[(n0 + 16 + q * 4 + r) * OO + o0 + r16]      = acc10[r];
            out[(n0 + 16 + q * 4 + r) * OO + o0 + 16 + r16] = acc11[r];
        }
    } else {
        unsigned short* pp = parts + (ks - 1) * (NV * OO);
        #pragma unroll
        for (int r = 0; r < 4; r++) {
            pp[(n0 + q * 4 + r) * OO + o0 + r16]           = f2h(acc00[r]);
            pp[(n0 + q * 4 + r) * OO + o0 + 16 + r16]      = f2h(acc01[r]);
            pp[(n0 + 16 + q * 4 + r) * OO + o0 + r16]      = f2h(acc10[r]);
            pp[(n0 + 16 + q * 4 + r) * OO + o0 + 16 + r16] = f2h(acc11[r]);
        }
    }
}

// ---------------------------------------------------------------------------
// Epilogue: v = part0(out) + part1+part2+part3 + bg; out = v*rsqrt(sum v^2).
// 32 rows/block, 8 threads per row. Reads then fully overwrites d_out.
// ---------------------------------------------------------------------------
__global__ __launch_bounds__(256) void norm_kernel(
    float* __restrict__ out, const unsigned short* __restrict__ parts,
    const float* __restrict__ bg) {
    const int tid = threadIdx.x;
    const int n   = blockIdx.x * 32 + (tid >> 3);
    const int l   = tid & 7;
    float v[16];
    float s = 0.f;
    #pragma unroll
    for (int i = 0; i < 16; i++) {
        const int o = i * 8 + l;
        const int e = n * OO + o;
        v[i] = out[e] + h2f(parts[e]) + h2f(parts[NV * OO + e]) +
               h2f(parts[2 * NV * OO + e]) + bg[o];
        s += v[i] * v[i];
    }
    for (int off = 4; off; off >>= 1) s += __shfl_down(s, off, 8);
    const float r = rsqrtf(__shfl(s, 0, 8));
    #pragma unroll
    for (int i = 0; i < 16; i++)
        out[n * OO + i * 8 + l] = v[i] * r;
}

// ---------------------------------------------------------------------------
extern "C" void kernel_launch(void* const* d_in, const int* in_sizes, int n_in,
                              void* d_out, int out_size, void* d_ws, size_t ws_size,
                              hipStream_t stream) {
    const float* x        = (const float*)d_in[0];
    const int*   conn_idx = (const int*)  d_in[1];
    const float* conn_w   = (const float*)d_in[2];
    const float* W1       = (const float*)d_in[3];
    const float* Wg       = (const float*)d_in[4];
    const float* bg       = (const float*)d_in[5];
    float*       out      = (float*)d_out;

    unsigned short* W2    = (unsigned short*)d_ws;         // 655,360 fp16 (1.31 MB)
    unsigned short* hb    = W2 + OO * KTOT;                // 1,280,000 fp16 (2.56 MB)
    unsigned short* parts = hb + NV * HH;                  // 3 x 2,560,000 fp16 (15.4 MB)

    hipLaunchKernelGGL(prep_kernel, dim3(128 + NV / 32), dim3(256), 0, stream,
                       Wg, x, W1, W2, hb);
    hipLaunchKernelGGL(geo_kernel, dim3(4 * NV / NB), dim3(256), 0, stream,
                       conn_idx, conn_w, W2, hb, out, parts);
    hipLaunchKernelGGL(norm_kernel, dim3(NV / 32), dim3(256), 0, stream,
                       out, parts, bg);
}

// Round 9
// 181.816 us; speedup vs baseline: 1.9445x; 1.0308x over previous
//
#include <hip/hip_runtime.h>
#include <hip/hip_fp16.h>

// Problem constants
#define NV   20000
#define KK   3
#define INF  150
#define HH   64
#define OO   128
#define PT   80
#define KTOT 5120      // 80 bins * 64 h
#define NB   32        // vertices per geo block
#define BS2  72        // per-bin stride in pch, halves (64 + 8 pad)
#define RS2  152       // 2-bin row stride = 2*BS2 + 8 halves (76 words %32 == 12)
#define CHB  (NB * RS2)   // 4864 halves = 9728 B per buffer
#define XS   168       // x/W1 LDS col stride, halves
#define NSUB 10        // sub-chunks per block (20 bins / 2)

typedef _Float16 fh8 __attribute__((ext_vector_type(8)));   // MFMA A/B frag (4 VGPRs)
typedef __attribute__((ext_vector_type(4))) float f32x4;    // MFMA C/D frag

__device__ __forceinline__ unsigned short f2h(float f) {
    return __half_as_ushort(__float2half(f));
}
__device__ __forceinline__ float h2f(unsigned short u) {
    return __half2float(__ushort_as_half(u));
}

struct Conn { int idx[6]; float w[6]; };   // 2 vertex-groups x 3 neighbors

// ---------------------------------------------------------------------------
// Fused prep kernel (unchanged).
// Blocks 0..127: transpose Wg[o] -> W2 [S][o][kk] fp16 via LDS.
// Blocks 128..752: h = relu(x @ W1^T) -> fp16, 32 rows/block via MFMA.
// ---------------------------------------------------------------------------
__global__ __launch_bounds__(256) void prep_kernel(
    const float* __restrict__ Wg, const float* __restrict__ x,
    const float* __restrict__ W1, unsigned short* __restrict__ W2,
    unsigned short* __restrict__ hb) {
    __shared__ __align__(16) unsigned char smem[32256];
    const int tid = threadIdx.x;

    if (blockIdx.x < 128) {
        float* lds = (float*)smem;                 // 64*81 words
        const int o = blockIdx.x;
        const float* src = Wg + o * KTOT;
        for (int t = tid; t < KTOT; t += 256) {    // t = h*80 + bin
            int h = t / 80, bin = t - h * 80;
            lds[h * 81 + bin] = src[t];
        }
        __syncthreads();
        for (int t = tid; t < KTOT; t += 256) {    // t = k = bin*64 + h
            W2[(t >> 5) * 4096 + o * 32 + (t & 31)] =
                f2h(lds[(t & 63) * 81 + (t >> 6)]);
        }
        return;
    }

    unsigned short* xs = (unsigned short*)smem;    // 32*168
    unsigned short* ws = xs + 32 * XS;             // 64*168
    const int n0 = (blockIdx.x - 128) * 32;

    for (int e = tid; e < 32 * INF; e += 256) {
        int r = e / INF, c = e - r * INF;
        xs[r * XS + c] = f2h(x[n0 * INF + e]);
    }
    for (int e = tid; e < 32 * 18; e += 256) {
        int r = e / 18, c = e - r * 18;
        xs[r * XS + 150 + c] = 0;
    }
    for (int e = tid; e < 64 * INF; e += 256) {
        int r = e / INF, c = e - r * INF;
        ws[r * XS + c] = f2h(W1[e]);
    }
    for (int e = tid; e < 64 * 18; e += 256) {
        int r = e / 18, c = e - r * 18;
        ws[r * XS + 150 + c] = 0;
    }
    __syncthreads();

    const int wv   = tid >> 6;
    const int lane = tid & 63;
    const int q    = lane >> 4;
    const int r16  = lane & 15;
    const int o0   = wv * 16;

    f32x4 acc0 = {0.f, 0.f, 0.f, 0.f};
    f32x4 acc1 = acc0;
    #pragma unroll
    for (int s = 0; s < 5; s++) {
        const int kb = s * 32 + q * 8;
        fh8 a0 = *(const fh8*)(xs + r16 * XS + kb);
        fh8 a1 = *(const fh8*)(xs + (16 + r16) * XS + kb);
        fh8 b  = *(const fh8*)(ws + (o0 + r16) * XS + kb);
        acc0 = __builtin_amdgcn_mfma_f32_16x16x32_f16(a0, b, acc0, 0, 0, 0);
        acc1 = __builtin_amdgcn_mfma_f32_16x16x32_f16(a1, b, acc1, 0, 0, 0);
    }
    #pragma unroll
    for (int r = 0; r < 4; r++) {
        float v0 = acc0[r] > 0.f ? acc0[r] : 0.f;
        float v1 = acc1[r] > 0.f ? acc1[r] : 0.f;
        hb[(n0 + q * 4 + r) * HH + o0 + r16]      = f2h(v0);
        hb[(n0 + 16 + q * 4 + r) * HH + o0 + r16] = f2h(v1);
    }
}

// ---------------------------------------------------------------------------
// Split-K x4 geo kernel, conn hoisted out of the K-loop.
// Grid 2500 = 625 n-blocks x 4 K-slices (20 bins each).
// One-time COALESCED preload of this block's conn slice into LDS (ci/cw,
// 15.4 KB, 60 contiguous dwords per vertex row) — the steady-state body has
// ZERO cold-HBM loads, so the pre-barrier vmcnt drain waits only on L2-hot
// gathers/W2 (~300cyc) instead of streamed conn (~1-2K cyc).
// Per sub-chunk (2 bins, 128 k): conn(cc+1) from LDS -> regs, gathers(cc+1)
// -> regs (in flight across MFMA), 4 MFMA k-steps on current buffer,
// combine+write other buffer, 1 barrier.
// Deterministic partials: ks=0 -> fp32 d_out, ks>=1 -> fp16 parts[ks-1].
// LDS 34.8 KB -> 4 blocks/CU cap.
// ---------------------------------------------------------------------------
__global__ __launch_bounds__(256, 4) void geo_kernel(
    const int*   __restrict__ conn_idx, const float* __restrict__ conn_w,
    const unsigned short* __restrict__ W2, const unsigned short* __restrict__ hb,
    float* __restrict__ out, unsigned short* __restrict__ parts) {
    __shared__ __align__(16) unsigned short pch[2 * CHB];  // 19456 B
    __shared__ int   ci[NB * 60];                          // 7680 B
    __shared__ float cw[NB * 60];                          // 7680 B

    const int tid  = threadIdx.x;
    const int ks   = blockIdx.x & 3;             // K-slice 0..3
    const int n0   = (blockIdx.x >> 2) * NB;
    const int wv   = tid >> 6;
    const int lane = tid & 63;
    const int q    = lane >> 4;
    const int r16  = lane & 15;
    const int j8   = tid & 7;                    // 16B segment of h row
    const int bl   = (tid >> 3) & 1;             // bin within sub-chunk
    const int ng   = tid >> 4;                   // vertex sub-row 0..15
    const int bbase = ks * 20;                   // first bin of this K-slice
    const int Sbase = ks * 40;                   // first 32-k step

    // One-time conn preload: rows of 60 contiguous dwords -> coalesced.
    for (int e = tid; e < NB * 60; e += 256) {
        const int r = e / 60, c = e - r * 60;
        const int g = (n0 + r) * (PT * KK) + bbase * KK + c;
        ci[e] = conn_idx[g];
        cw[e] = conn_w[g];
    }

    f32x4 acc00 = {0.f, 0.f, 0.f, 0.f};
    f32x4 acc01 = acc00, acc10 = acc00, acc11 = acc00;

    Conn cN;
    fh8  hv[6];

    auto loadc = [&](int cc, Conn& c) {          // conn from LDS (broadcast)
        const int bo = (cc * 2 + bl) * 3;
        #pragma unroll
        for (int i = 0; i < 2; i++) {
            const int base = (ng + i * 16) * 60 + bo;
            c.idx[i * 3 + 0] = ci[base];
            c.idx[i * 3 + 1] = ci[base + 1];
            c.idx[i * 3 + 2] = ci[base + 2];
            c.w[i * 3 + 0]   = cw[base];
            c.w[i * 3 + 1]   = cw[base + 1];
            c.w[i * 3 + 2]   = cw[base + 2];
        }
    };
    auto loadh = [&](const Conn& c) {            // gather h rows -> regs (L2)
        #pragma unroll
        for (int t = 0; t < 6; t++)
            hv[t] = *(const fh8*)(hb + c.idx[t] * HH + j8 * 8);
    };
    auto cwrite = [&](const Conn& c, unsigned short* buf) {  // combine + LDS
        #pragma unroll
        for (int i = 0; i < 2; i++) {
            const int n = ng + i * 16;
            _Float16 w0 = (_Float16)c.w[i * 3 + 0];
            _Float16 w1 = (_Float16)c.w[i * 3 + 1];
            _Float16 w2 = (_Float16)c.w[i * 3 + 2];
            fh8 W0 = {w0, w0, w0, w0, w0, w0, w0, w0};
            fh8 W1v = {w1, w1, w1, w1, w1, w1, w1, w1};
            fh8 W2v = {w2, w2, w2, w2, w2, w2, w2, w2};
            fh8 r = hv[i * 3] * W0 + hv[i * 3 + 1] * W1v + hv[i * 3 + 2] * W2v;
            *(fh8*)(buf + n * RS2 + bl * BS2 + j8 * 8) = r;
        }
    };
    auto mfmaph = [&](const unsigned short* buf, int cc) {   // 4 k-steps
        #pragma unroll
        for (int s = 0; s < 4; s++) {
            const int S  = Sbase + cc * 4 + s;
            const int ao = (s >> 1) * BS2 + (s & 1) * 32 + q * 8;
            fh8 a0 = *(const fh8*)(buf + r16 * RS2 + ao);
            fh8 a1 = *(const fh8*)(buf + (16 + r16) * RS2 + ao);
            fh8 b0 = *(const fh8*)(W2 + S * 4096 + (wv * 32 + r16) * 32 + q * 8);
            fh8 b1 = *(const fh8*)(W2 + S * 4096 + (wv * 32 + 16 + r16) * 32 + q * 8);
            acc00 = __builtin_amdgcn_mfma_f32_16x16x32_f16(a0, b0, acc00, 0, 0, 0);
            acc01 = __builtin_amdgcn_mfma_f32_16x16x32_f16(a0, b1, acc01, 0, 0, 0);
            acc10 = __builtin_amdgcn_mfma_f32_16x16x32_f16(a1, b0, acc10, 0, 0, 0);
            acc11 = __builtin_amdgcn_mfma_f32_16x16x32_f16(a1, b1, acc11, 0, 0, 0);
        }
    };

    __syncthreads();                             // ci/cw visible

    // Prologue: sub-chunk 0 staged into buffer 0
    loadc(0, cN);
    loadh(cN);
    cwrite(cN, pch);
    __syncthreads();

    for (int cc = 0; cc < NSUB; cc++) {
        if (cc + 1 < NSUB) {
            loadc(cc + 1, cN);                   // LDS, cheap
            loadh(cN);                           // L2 gathers, in flight
        }
        mfmaph(&pch[(cc & 1) * CHB], cc);        //   across the MFMA phase
        if (cc + 1 < NSUB) cwrite(cN, &pch[((cc + 1) & 1) * CHB]);
        __syncthreads();
    }

    // Partial store. D layout: row = q*4+reg, col = r16. Exactly one writer
    // per element per stage -> deterministic, pure overwrite.
    const int o0 = wv * 32;
    if (ks == 0) {
        #pragma unroll
        for (int r = 0; r < 4; r++) {
            out[(n0 + q * 4 + r) * OO + o0 + r16]           = acc00[r];
            out[(n0 + q * 4 + r) * OO + o0 + 16 + r16]      = acc01[r];
            out[(n0 + 16 + q * 4 + r) * OO + o0 + r16]      = acc10[r];
            out[(n0 + 16 + q * 4 + r) * OO + o0 + 16 + r16] = acc11[r];
        }
    } else {
        unsigned short* pp = parts + (ks - 1) * (NV * OO);
        #pragma unroll
        for (int r = 0; r < 4; r++) {
            pp[(n0 + q * 4 + r) * OO + o0 + r16]           = f2h(acc00[r]);
            pp[(n0 + q * 4 + r) * OO + o0 + 16 + r16]      = f2h(acc01[r]);
            pp[(n0 + 16 + q * 4 + r) * OO + o0 + r16]      = f2h(acc10[r]);
            pp[(n0 + 16 + q * 4 + r) * OO + o0 + 16 + r16] = f2h(acc11[r]);
        }
    }
}

// ---------------------------------------------------------------------------
// Epilogue: v = part0(out) + part1+part2+part3 + bg; out = v*rsqrt(sum v^2).
// 32 rows/block, 8 threads per row. Reads then fully overwrites d_out.
// ---------------------------------------------------------------------------
__global__ __launch_bounds__(256) void norm_kernel(
    float* __restrict__ out, const unsigned short* __restrict__ parts,
    const float* __restrict__ bg) {
    const int tid = threadIdx.x;
    const int n   = blockIdx.x * 32 + (tid >> 3);
    const int l   = tid & 7;
    float v[16];
    float s = 0.f;
    #pragma unroll
    for (int i = 0; i < 16; i++) {
        const int o = i * 8 + l;
        const int e = n * OO + o;
        v[i] = out[e] + h2f(parts[e]) + h2f(parts[NV * OO + e]) +
               h2f(parts[2 * NV * OO + e]) + bg[o];
        s += v[i] * v[i];
    }
    for (int off = 4; off; off >>= 1) s += __shfl_down(s, off, 8);
    const float r = rsqrtf(__shfl(s, 0, 8));
    #pragma unroll
    for (int i = 0; i < 16; i++)
        out[n * OO + i * 8 + l] = v[i] * r;
}

// ---------------------------------------------------------------------------
extern "C" void kernel_launch(void* const* d_in, const int* in_sizes, int n_in,
                              void* d_out, int out_size, void* d_ws, size_t ws_size,
                              hipStream_t stream) {
    const float* x        = (const float*)d_in[0];
    const int*   conn_idx = (const int*)  d_in[1];
    const float* conn_w   = (const float*)d_in[2];
    const float* W1       = (const float*)d_in[3];
    const float* Wg       = (const float*)d_in[4];
    const float* bg       = (const float*)d_in[5];
    float*       out      = (float*)d_out;

    unsigned short* W2    = (unsigned short*)d_ws;         // 655,360 fp16 (1.31 MB)
    unsigned short* hb    = W2 + OO * KTOT;                // 1,280,000 fp16 (2.56 MB)
    unsigned short* parts = hb + NV * HH;                  // 3 x 2,560,000 fp16 (15.4 MB)

    hipLaunchKernelGGL(prep_kernel, dim3(128 + NV / 32), dim3(256), 0, stream,
                       Wg, x, W1, W2, hb);
    hipLaunchKernelGGL(geo_kernel, dim3(4 * NV / NB), dim3(256), 0, stream,
                       conn_idx, conn_w, W2, hb, out, parts);
    hipLaunchKernelGGL(norm_kernel, dim3(NV / 32), dim3(256), 0, stream,
                       out, parts, bg);
}

// Round 10
// 180.534 us; speedup vs baseline: 1.9583x; 1.0071x over previous
//
#include <hip/hip_runtime.h>
#include <hip/hip_fp16.h>

// Problem constants
#define NV   20000
#define KK   3
#define INF  150
#define HH   64
#define OO   128
#define PT   80
#define KTOT 5120      // 80 bins * 64 h
#define NB   64        // vertices per geo block
#define RS   72        // pch v-row stride, halves (64 + 8 pad; 144 B, 16B-aligned)
#define CB   (NB * RS) // 4608 halves = 9216 B per buffer
#define XS   168       // x/W1 LDS col stride, halves (prep kernel)
#define NBIN 20        // bins per K-slice

typedef _Float16 fh8 __attribute__((ext_vector_type(8)));   // MFMA A/B frag (4 VGPRs)
typedef __attribute__((ext_vector_type(4))) float f32x4;    // MFMA C/D frag

__device__ __forceinline__ unsigned short f2h(float f) {
    return __half_as_ushort(__float2half(f));
}
__device__ __forceinline__ float h2f(unsigned short u) {
    return __half2float(__ushort_as_half(u));
}
__device__ __forceinline__ _Float16 u2h(unsigned short u) {
    union { unsigned short s; _Float16 h; } c; c.s = u; return c.h;
}

// ---------------------------------------------------------------------------
// Fused prep kernel (unchanged).
// Blocks 0..127: transpose Wg[o] -> W2 [S][o][kk] fp16 via LDS.
// Blocks 128..752: h = relu(x @ W1^T) -> fp16, 32 rows/block via MFMA.
// ---------------------------------------------------------------------------
__global__ __launch_bounds__(256) void prep_kernel(
    const float* __restrict__ Wg, const float* __restrict__ x,
    const float* __restrict__ W1, unsigned short* __restrict__ W2,
    unsigned short* __restrict__ hb) {
    __shared__ __align__(16) unsigned char smem[32256];
    const int tid = threadIdx.x;

    if (blockIdx.x < 128) {
        float* lds = (float*)smem;                 // 64*81 words
        const int o = blockIdx.x;
        const float* src = Wg + o * KTOT;
        for (int t = tid; t < KTOT; t += 256) {    // t = h*80 + bin
            int h = t / 80, bin = t - h * 80;
            lds[h * 81 + bin] = src[t];
        }
        __syncthreads();
        for (int t = tid; t < KTOT; t += 256) {    // t = k = bin*64 + h
            W2[(t >> 5) * 4096 + o * 32 + (t & 31)] =
                f2h(lds[(t & 63) * 81 + (t >> 6)]);
        }
        return;
    }

    unsigned short* xs = (unsigned short*)smem;    // 32*168
    unsigned short* ws = xs + 32 * XS;             // 64*168
    const int n0 = (blockIdx.x - 128) * 32;

    for (int e = tid; e < 32 * INF; e += 256) {
        int r = e / INF, c = e - r * INF;
        xs[r * XS + c] = f2h(x[n0 * INF + e]);
    }
    for (int e = tid; e < 32 * 18; e += 256) {
        int r = e / 18, c = e - r * 18;
        xs[r * XS + 150 + c] = 0;
    }
    for (int e = tid; e < 64 * INF; e += 256) {
        int r = e / INF, c = e - r * INF;
        ws[r * XS + c] = f2h(W1[e]);
    }
    for (int e = tid; e < 64 * 18; e += 256) {
        int r = e / 18, c = e - r * 18;
        ws[r * XS + 150 + c] = 0;
    }
    __syncthreads();

    const int wv   = tid >> 6;
    const int lane = tid & 63;
    const int q    = lane >> 4;
    const int r16  = lane & 15;
    const int o0   = wv * 16;

    f32x4 acc0 = {0.f, 0.f, 0.f, 0.f};
    f32x4 acc1 = acc0;
    #pragma unroll
    for (int s = 0; s < 5; s++) {
        const int kb = s * 32 + q * 8;
        fh8 a0 = *(const fh8*)(xs + r16 * XS + kb);
        fh8 a1 = *(const fh8*)(xs + (16 + r16) * XS + kb);
        fh8 b  = *(const fh8*)(ws + (o0 + r16) * XS + kb);
        acc0 = __builtin_amdgcn_mfma_f32_16x16x32_f16(a0, b, acc0, 0, 0, 0);
        acc1 = __builtin_amdgcn_mfma_f32_16x16x32_f16(a1, b, acc1, 0, 0, 0);
    }
    #pragma unroll
    for (int r = 0; r < 4; r++) {
        float v0 = acc0[r] > 0.f ? acc0[r] : 0.f;
        float v1 = acc1[r] > 0.f ? acc1[r] : 0.f;
        hb[(n0 + q * 4 + r) * HH + o0 + r16]      = f2h(v0);
        hb[(n0 + 16 + q * 4 + r) * HH + o0 + r16] = f2h(v1);
    }
}

// ---------------------------------------------------------------------------
// Geo kernel, NB=64 / 512-thread / split-K x4. Grid 1252 = 313 n-blocks x 4.
// Rationale (R9 post-mortem): kernel is L1-line-throughput bound; W2 traffic
// scales with n-block count -> NB 32->64 halves it (818->409 MB); 8-wave
// blocks + 33.6 KB LDS -> 3 blocks/CU = 24 waves/CU doubles line-issue MLP.
// conn compressed in LDS (u16 idx + f16 w). 1-bin sub-chunks, double-buffered
// pch, gathers for bin cc+1 in flight across the 8-MFMA phase of bin cc,
// one barrier per bin. Wave wv: m-pair mp=wv&1 (m-frags 2mp,2mp+1),
// o-pair op=wv>>1 (o-tiles 2op,2op+1) -> per-sub-chunk W2 working set 16 KB
// stays L1-resident across the block's waves.
// Deterministic partials: ks=0 -> fp32 d_out, ks>=1 -> fp16 parts[ks-1].
// ---------------------------------------------------------------------------
__global__ __launch_bounds__(512, 6) void geo_kernel(
    const int*   __restrict__ conn_idx, const float* __restrict__ conn_w,
    const unsigned short* __restrict__ W2, const unsigned short* __restrict__ hb,
    float* __restrict__ out, unsigned short* __restrict__ parts) {
    __shared__ __align__(16) unsigned short pch[2 * CB];   // 18432 B
    __shared__ unsigned short ci[NB * 60];                 // 7680 B (u16 idx)
    __shared__ unsigned short cw[NB * 60];                 // 7680 B (f16 w)

    const int tid  = threadIdx.x;
    const int ks   = blockIdx.x & 3;             // K-slice 0..3
    const int n0   = (blockIdx.x >> 2) * NB;
    const int wv   = tid >> 6;                   // wave 0..7
    const int lane = tid & 63;
    const int q    = lane >> 4;
    const int r16  = lane & 15;
    const int mp   = wv & 1;                     // m-pair
    const int op   = wv >> 1;                    // o-pair
    const int j8   = tid & 7;                    // 16B segment of h row
    const int vg   = tid >> 3;                   // vertex 0..63
    const int bbase = ks * NBIN;                 // first bin of this K-slice
    const int Sbase = ks * 40;                   // first 32-k step

    // One-time conn preload: 60 contiguous dwords per vertex row, coalesced,
    // compressed to u16/f16 (idx < 20000 fits u16).
    for (int e = tid; e < NB * 60; e += 512) {
        const int r = e / 60, c = e - r * 60;
        const int v = n0 + r;
        if (v < NV) {
            const int g = v * (PT * KK) + bbase * KK + c;
            ci[e] = (unsigned short)conn_idx[g];
            cw[e] = f2h(conn_w[g]);
        } else {
            ci[e] = 0;
            cw[e] = 0;
        }
    }

    f32x4 acc00 = {0.f, 0.f, 0.f, 0.f};
    f32x4 acc01 = acc00, acc10 = acc00, acc11 = acc00;

    fh8 hv0, hv1, hv2;
    unsigned short w0u, w1u, w2u;

    auto loadg = [&](int cc) {                   // gathers for bin cc -> regs
        const int base = vg * 60 + cc * 3;
        const int i0 = ci[base], i1 = ci[base + 1], i2 = ci[base + 2];
        w0u = cw[base]; w1u = cw[base + 1]; w2u = cw[base + 2];
        hv0 = *(const fh8*)(hb + i0 * HH + j8 * 8);
        hv1 = *(const fh8*)(hb + i1 * HH + j8 * 8);
        hv2 = *(const fh8*)(hb + i2 * HH + j8 * 8);
    };
    auto cwr = [&](unsigned short* buf) {        // combine + LDS write
        const _Float16 w0 = u2h(w0u), w1 = u2h(w1u), w2 = u2h(w2u);
        const fh8 W0 = {w0, w0, w0, w0, w0, w0, w0, w0};
        const fh8 W1v = {w1, w1, w1, w1, w1, w1, w1, w1};
        const fh8 W2v = {w2, w2, w2, w2, w2, w2, w2, w2};
        fh8 r = hv0 * W0 + hv1 * W1v + hv2 * W2v;
        *(fh8*)(buf + vg * RS + j8 * 8) = r;
    };
    auto mfmaph = [&](const unsigned short* buf, int cc) {   // 2 k-steps
        #pragma unroll
        for (int s = 0; s < 2; s++) {
            const int S  = Sbase + cc * 2 + s;
            const int ao = s * 32 + q * 8;
            fh8 a0 = *(const fh8*)(buf + (mp * 32 + r16) * RS + ao);
            fh8 a1 = *(const fh8*)(buf + (mp * 32 + 16 + r16) * RS + ao);
            fh8 b0 = *(const fh8*)(W2 + S * 4096 + ((op * 2 + 0) * 16 + r16) * 32 + q * 8);
            fh8 b1 = *(const fh8*)(W2 + S * 4096 + ((op * 2 + 1) * 16 + r16) * 32 + q * 8);
            acc00 = __builtin_amdgcn_mfma_f32_16x16x32_f16(a0, b0, acc00, 0, 0, 0);
            acc01 = __builtin_amdgcn_mfma_f32_16x16x32_f16(a0, b1, acc01, 0, 0, 0);
            acc10 = __builtin_amdgcn_mfma_f32_16x16x32_f16(a1, b0, acc10, 0, 0, 0);
            acc11 = __builtin_amdgcn_mfma_f32_16x16x32_f16(a1, b1, acc11, 0, 0, 0);
        }
    };

    __syncthreads();                             // ci/cw visible

    // Prologue: bin 0 staged into buffer 0
    loadg(0);
    cwr(pch);
    __syncthreads();

    for (int cc = 0; cc < NBIN; cc++) {
        if (cc + 1 < NBIN) loadg(cc + 1);        // gathers in flight across
        mfmaph(&pch[(cc & 1) * CB], cc);         //   the MFMA phase
        if (cc + 1 < NBIN) cwr(&pch[((cc + 1) & 1) * CB]);
        __syncthreads();
    }

    // Partial store. D layout: row = q*4+reg, col = r16. One writer per
    // element per stage -> deterministic, pure overwrite. Guard row < NV
    // (last n-block covers only 32 valid vertices).
    if (ks == 0) {
        #pragma unroll
        for (int a = 0; a < 2; a++) {
            const int rb = n0 + (2 * mp + a) * 16 + q * 4;
            #pragma unroll
            for (int r = 0; r < 4; r++) {
                if (rb + r < NV) {
                    out[(rb + r) * OO + (2 * op + 0) * 16 + r16] = a ? acc10[r] : acc00[r];
                    out[(rb + r) * OO + (2 * op + 1) * 16 + r16] = a ? acc11[r] : acc01[r];
                }
            }
        }
    } else {
        unsigned short* pp = parts + (ks - 1) * (NV * OO);
        #pragma unroll
        for (int a = 0; a < 2; a++) {
            const int rb = n0 + (2 * mp + a) * 16 + q * 4;
            #pragma unroll
            for (int r = 0; r < 4; r++) {
                if (rb + r < NV) {
                    pp[(rb + r) * OO + (2 * op + 0) * 16 + r16] = f2h(a ? acc10[r] : acc00[r]);
                    pp[(rb + r) * OO + (2 * op + 1) * 16 + r16] = f2h(a ? acc11[r] : acc01[r]);
                }
            }
        }
    }
}

// ---------------------------------------------------------------------------
// Epilogue: v = part0(out) + part1+part2+part3 + bg; out = v*rsqrt(sum v^2).
// 32 rows/block, 8 threads per row. Reads then fully overwrites d_out.
// ---------------------------------------------------------------------------
__global__ __launch_bounds__(256) void norm_kernel(
    float* __restrict__ out, const unsigned short* __restrict__ parts,
    const float* __restrict__ bg) {
    const int tid = threadIdx.x;
    const int n   = blockIdx.x * 32 + (tid >> 3);
    const int l   = tid & 7;
    float v[16];
    float s = 0.f;
    #pragma unroll
    for (int i = 0; i < 16; i++) {
        const int o = i * 8 + l;
        const int e = n * OO + o;
        v[i] = out[e] + h2f(parts[e]) + h2f(parts[NV * OO + e]) +
               h2f(parts[2 * NV * OO + e]) + bg[o];
        s += v[i] * v[i];
    }
    for (int off = 4; off; off >>= 1) s += __shfl_down(s, off, 8);
    const float r = rsqrtf(__shfl(s, 0, 8));
    #pragma unroll
    for (int i = 0; i < 16; i++)
        out[n * OO + i * 8 + l] = v[i] * r;
}

// ---------------------------------------------------------------------------
extern "C" void kernel_launch(void* const* d_in, const int* in_sizes, int n_in,
                              void* d_out, int out_size, void* d_ws, size_t ws_size,
                              hipStream_t stream) {
    const float* x        = (const float*)d_in[0];
    const int*   conn_idx = (const int*)  d_in[1];
    const float* conn_w   = (const float*)d_in[2];
    const float* W1       = (const float*)d_in[3];
    const float* Wg       = (const float*)d_in[4];
    const float* bg       = (const float*)d_in[5];
    float*       out      = (float*)d_out;

    unsigned short* W2    = (unsigned short*)d_ws;         // 655,360 fp16 (1.31 MB)
    unsigned short* hb    = W2 + OO * KTOT;                // 1,280,000 fp16 (2.56 MB)
    unsigned short* parts = hb + NV * HH;                  // 3 x 2,560,000 fp16 (15.4 MB)

    hipLaunchKernelGGL(prep_kernel, dim3(128 + NV / 32), dim3(256), 0, stream,
                       Wg, x, W1, W2, hb);
    hipLaunchKernelGGL(geo_kernel, dim3(4 * 313), dim3(512), 0, stream,
                       conn_idx, conn_w, W2, hb, out, parts);
    hipLaunchKernelGGL(norm_kernel, dim3(NV / 32), dim3(256), 0, stream,
                       out, parts, bg);
}

// Round 11
// 174.018 us; speedup vs baseline: 2.0316x; 1.0374x over previous
//
#include <hip/hip_runtime.h>
#include <hip/hip_fp16.h>

// Problem constants
#define NV   20000
#define KK   3
#define INF  150
#define HH   64
#define OO   128
#define PT   80
#define KTOT 5120      // 80 bins * 64 h
#define NB   64        // vertices per geo block
#define RS   72        // pch v-row stride, halves (64 + 8 pad)
#define CB   (NB * RS) // 4608 halves = 9216 B per buffer
#define XS   168       // x/W1 LDS col stride, halves (prep kernel)
#define NBIN 20        // bins per K-slice

typedef _Float16 fh8 __attribute__((ext_vector_type(8)));   // MFMA A/B frag (4 VGPRs)
typedef __attribute__((ext_vector_type(4))) float f32x4;    // MFMA C/D frag
typedef __attribute__((ext_vector_type(8))) unsigned short u16x8;

__device__ __forceinline__ unsigned short f2h(float f) {
    return __half_as_ushort(__float2half(f));
}
__device__ __forceinline__ float h2f(unsigned short u) {
    return __half2float(__ushort_as_half(u));
}
__device__ __forceinline__ _Float16 u2h(unsigned short u) {
    union { unsigned short s; _Float16 h; } c; c.s = u; return c.h;
}

// ---------------------------------------------------------------------------
// Fused prep kernel (unchanged).
// Blocks 0..127: transpose Wg[o] -> W2 [S][o][kk] fp16 via LDS.
// Blocks 128..752: h = relu(x @ W1^T) -> fp16, 32 rows/block via MFMA.
// ---------------------------------------------------------------------------
__global__ __launch_bounds__(256) void prep_kernel(
    const float* __restrict__ Wg, const float* __restrict__ x,
    const float* __restrict__ W1, unsigned short* __restrict__ W2,
    unsigned short* __restrict__ hb) {
    __shared__ __align__(16) unsigned char smem[32256];
    const int tid = threadIdx.x;

    if (blockIdx.x < 128) {
        float* lds = (float*)smem;                 // 64*81 words
        const int o = blockIdx.x;
        const float* src = Wg + o * KTOT;
        for (int t = tid; t < KTOT; t += 256) {    // t = h*80 + bin
            int h = t / 80, bin = t - h * 80;
            lds[h * 81 + bin] = src[t];
        }
        __syncthreads();
        for (int t = tid; t < KTOT; t += 256) {    // t = k = bin*64 + h
            W2[(t >> 5) * 4096 + o * 32 + (t & 31)] =
                f2h(lds[(t & 63) * 81 + (t >> 6)]);
        }
        return;
    }

    unsigned short* xs = (unsigned short*)smem;    // 32*168
    unsigned short* ws = xs + 32 * XS;             // 64*168
    const int n0 = (blockIdx.x - 128) * 32;

    for (int e = tid; e < 32 * INF; e += 256) {
        int r = e / INF, c = e - r * INF;
        xs[r * XS + c] = f2h(x[n0 * INF + e]);
    }
    for (int e = tid; e < 32 * 18; e += 256) {
        int r = e / 18, c = e - r * 18;
        xs[r * XS + 150 + c] = 0;
    }
    for (int e = tid; e < 64 * INF; e += 256) {
        int r = e / INF, c = e - r * INF;
        ws[r * XS + c] = f2h(W1[e]);
    }
    for (int e = tid; e < 64 * 18; e += 256) {
        int r = e / 18, c = e - r * 18;
        ws[r * XS + 150 + c] = 0;
    }
    __syncthreads();

    const int wv   = tid >> 6;
    const int lane = tid & 63;
    const int q    = lane >> 4;
    const int r16  = lane & 15;
    const int o0   = wv * 16;

    f32x4 acc0 = {0.f, 0.f, 0.f, 0.f};
    f32x4 acc1 = acc0;
    #pragma unroll
    for (int s = 0; s < 5; s++) {
        const int kb = s * 32 + q * 8;
        fh8 a0 = *(const fh8*)(xs + r16 * XS + kb);
        fh8 a1 = *(const fh8*)(xs + (16 + r16) * XS + kb);
        fh8 b  = *(const fh8*)(ws + (o0 + r16) * XS + kb);
        acc0 = __builtin_amdgcn_mfma_f32_16x16x32_f16(a0, b, acc0, 0, 0, 0);
        acc1 = __builtin_amdgcn_mfma_f32_16x16x32_f16(a1, b, acc1, 0, 0, 0);
    }
    #pragma unroll
    for (int r = 0; r < 4; r++) {
        float v0 = acc0[r] > 0.f ? acc0[r] : 0.f;
        float v1 = acc1[r] > 0.f ? acc1[r] : 0.f;
        hb[(n0 + q * 4 + r) * HH + o0 + r16]      = f2h(v0);
        hb[(n0 + 16 + q * 4 + r) * HH + o0 + r16] = f2h(v1);
    }
}

// ---------------------------------------------------------------------------
// Geo kernel v10: 256-thr blocks, NB=64, split-K x4 (grid 1252 = 313 x 4).
// R10 post-mortem: TCP-line + LDS pipe throughput bound (occupancy 67% gave
// nothing). Cuts: (1) wave tile = 4 m-frags x 2 o-tiles -> exact cover of
// the 4m x 8o unit grid, NO duplicated B-frag loads (W2 TCP halved vs the
// 8-wave mp/op scheme); (2) conn packed [3xu16 idx|3xf16 w|pad] -> ONE
// ds_read_b128 per (vertex,bin) instead of 6 scalar LDS reads.
// Per bin: loadg(cc+1) [2 packed conn b128 + 6 gathers in flight across
// MFMA], 16 MFMA on buf[cc&1], combine+write buf[(cc+1)&1], 1 barrier.
// LDS 38.9 KB -> 4 blocks/CU = 16 waves/CU (TLP proven non-binding).
// Deterministic partials: ks=0 -> fp32 d_out, ks>=1 -> fp16 parts[ks-1].
// ---------------------------------------------------------------------------
__global__ __launch_bounds__(256, 4) void geo_kernel(
    const int*   __restrict__ conn_idx, const float* __restrict__ conn_w,
    const unsigned short* __restrict__ W2, const unsigned short* __restrict__ hb,
    float* __restrict__ out, unsigned short* __restrict__ parts) {
    __shared__ __align__(16) unsigned short pch[2 * CB];   // 18432 B
    __shared__ __align__(16) unsigned short cp[NB * NBIN * 8]; // 20480 B packed conn

    const int tid  = threadIdx.x;
    const int ks   = blockIdx.x & 3;             // K-slice 0..3
    const int n0   = (blockIdx.x >> 2) * NB;
    const int wv   = tid >> 6;                   // wave 0..3 = o-pair
    const int lane = tid & 63;
    const int q    = lane >> 4;
    const int r16  = lane & 15;
    const int j8   = tid & 7;                    // 16B segment of h row
    const int v0   = tid >> 3;                   // vertex 0..31 (also v0+32)
    const int bbase = ks * NBIN;
    const int Sbase = ks * 40;                   // first 32-k step

    // One-time conn preload, packed: cp[(v*20+cc)*8] = [i0,i1,i2,w0,w1,w2,0,0]
    // Global side: thread-unit (v,cc) reads 12B contiguous -> coalesced.
    for (int e = tid; e < NB * NBIN; e += 256) {
        const int v = e / NBIN, cc = e - v * NBIN;
        const int vv = n0 + v;
        u16x8 pk = {0, 0, 0, 0, 0, 0, 0, 0};
        if (vv < NV) {
            const int g = vv * (PT * KK) + (bbase + cc) * KK;
            pk[0] = (unsigned short)conn_idx[g];
            pk[1] = (unsigned short)conn_idx[g + 1];
            pk[2] = (unsigned short)conn_idx[g + 2];
            pk[3] = f2h(conn_w[g]);
            pk[4] = f2h(conn_w[g + 1]);
            pk[5] = f2h(conn_w[g + 2]);
        }
        *(u16x8*)(cp + e * 8) = pk;
    }

    f32x4 acc[4][2];
    #pragma unroll
    for (int m = 0; m < 4; m++) {
        acc[m][0] = (f32x4){0.f, 0.f, 0.f, 0.f};
        acc[m][1] = (f32x4){0.f, 0.f, 0.f, 0.f};
    }

    u16x8 pa, pb;        // packed conn for v0 and v0+32
    fh8   hva0, hva1, hva2, hvb0, hvb1, hvb2;

    auto loadg = [&](int cc) {                   // conn b128 + 6 gathers
        pa = *(const u16x8*)(cp + (v0 * NBIN + cc) * 8);
        pb = *(const u16x8*)(cp + ((v0 + 32) * NBIN + cc) * 8);
        hva0 = *(const fh8*)(hb + (int)pa[0] * HH + j8 * 8);
        hva1 = *(const fh8*)(hb + (int)pa[1] * HH + j8 * 8);
        hva2 = *(const fh8*)(hb + (int)pa[2] * HH + j8 * 8);
        hvb0 = *(const fh8*)(hb + (int)pb[0] * HH + j8 * 8);
        hvb1 = *(const fh8*)(hb + (int)pb[1] * HH + j8 * 8);
        hvb2 = *(const fh8*)(hb + (int)pb[2] * HH + j8 * 8);
    };
    auto cwr = [&](unsigned short* buf) {        // combine + 2 LDS b128 writes
        const _Float16 a0 = u2h(pa[3]), a1 = u2h(pa[4]), a2 = u2h(pa[5]);
        const _Float16 b0 = u2h(pb[3]), b1 = u2h(pb[4]), b2 = u2h(pb[5]);
        const fh8 A0 = {a0, a0, a0, a0, a0, a0, a0, a0};
        const fh8 A1 = {a1, a1, a1, a1, a1, a1, a1, a1};
        const fh8 A2 = {a2, a2, a2, a2, a2, a2, a2, a2};
        const fh8 B0 = {b0, b0, b0, b0, b0, b0, b0, b0};
        const fh8 B1 = {b1, b1, b1, b1, b1, b1, b1, b1};
        const fh8 B2 = {b2, b2, b2, b2, b2, b2, b2, b2};
        fh8 ra = hva0 * A0 + hva1 * A1 + hva2 * A2;
        fh8 rb = hvb0 * B0 + hvb1 * B1 + hvb2 * B2;
        *(fh8*)(buf + v0 * RS + j8 * 8)        = ra;
        *(fh8*)(buf + (v0 + 32) * RS + j8 * 8) = rb;
    };
    auto mfmaph = [&](const unsigned short* buf, int cc) {   // 16 MFMA
        #pragma unroll
        for (int s = 0; s < 2; s++) {
            const int S  = Sbase + cc * 2 + s;
            const int ao = s * 32 + q * 8;
            fh8 bf0 = *(const fh8*)(W2 + S * 4096 + ((wv * 2 + 0) * 16 + r16) * 32 + q * 8);
            fh8 bf1 = *(const fh8*)(W2 + S * 4096 + ((wv * 2 + 1) * 16 + r16) * 32 + q * 8);
            #pragma unroll
            for (int m = 0; m < 4; m++) {
                fh8 af = *(const fh8*)(buf + (m * 16 + r16) * RS + ao);
                acc[m][0] = __builtin_amdgcn_mfma_f32_16x16x32_f16(af, bf0, acc[m][0], 0, 0, 0);
                acc[m][1] = __builtin_amdgcn_mfma_f32_16x16x32_f16(af, bf1, acc[m][1], 0, 0, 0);
            }
        }
    };

    __syncthreads();                             // cp visible

    // Prologue: bin 0 staged into buffer 0
    loadg(0);
    cwr(pch);
    __syncthreads();

    for (int cc = 0; cc < NBIN; cc++) {
        if (cc + 1 < NBIN) loadg(cc + 1);        // gathers in flight across
        mfmaph(&pch[(cc & 1) * CB], cc);         //   the MFMA phase
        if (cc + 1 < NBIN) cwr(&pch[((cc + 1) & 1) * CB]);
        __syncthreads();
    }

    // Partial store. D layout: row = q*4+reg, col = r16. One writer per
    // element per stage -> deterministic, pure overwrite. Guard row < NV.
    if (ks == 0) {
        #pragma unroll
        for (int m = 0; m < 4; m++) {
            const int rb = n0 + m * 16 + q * 4;
            #pragma unroll
            for (int r = 0; r < 4; r++) {
                if (rb + r < NV) {
                    out[(rb + r) * OO + (wv * 2 + 0) * 16 + r16] = acc[m][0][r];
                    out[(rb + r) * OO + (wv * 2 + 1) * 16 + r16] = acc[m][1][r];
                }
            }
        }
    } else {
        unsigned short* pp = parts + (ks - 1) * (NV * OO);
        #pragma unroll
        for (int m = 0; m < 4; m++) {
            const int rb = n0 + m * 16 + q * 4;
            #pragma unroll
            for (int r = 0; r < 4; r++) {
                if (rb + r < NV) {
                    pp[(rb + r) * OO + (wv * 2 + 0) * 16 + r16] = f2h(acc[m][0][r]);
                    pp[(rb + r) * OO + (wv * 2 + 1) * 16 + r16] = f2h(acc[m][1][r]);
                }
            }
        }
    }
}

// ---------------------------------------------------------------------------
// Epilogue: v = part0(out) + part1+part2+part3 + bg; out = v*rsqrt(sum v^2).
// 32 rows/block, 8 threads per row. Reads then fully overwrites d_out.
// ---------------------------------------------------------------------------
__global__ __launch_bounds__(256) void norm_kernel(
    float* __restrict__ out, const unsigned short* __restrict__ parts,
    const float* __restrict__ bg) {
    const int tid = threadIdx.x;
    const int n   = blockIdx.x * 32 + (tid >> 3);
    const int l   = tid & 7;
    float v[16];
    float s = 0.f;
    #pragma unroll
    for (int i = 0; i < 16; i++) {
        const int o = i * 8 + l;
        const int e = n * OO + o;
        v[i] = out[e] + h2f(parts[e]) + h2f(parts[NV * OO + e]) +
               h2f(parts[2 * NV * OO + e]) + bg[o];
        s += v[i] * v[i];
    }
    for (int off = 4; off; off >>= 1) s += __shfl_down(s, off, 8);
    const float r = rsqrtf(__shfl(s, 0, 8));
    #pragma unroll
    for (int i = 0; i < 16; i++)
        out[n * OO + i * 8 + l] = v[i] * r;
}

// ---------------------------------------------------------------------------
extern "C" void kernel_launch(void* const* d_in, const int* in_sizes, int n_in,
                              void* d_out, int out_size, void* d_ws, size_t ws_size,
                              hipStream_t stream) {
    const float* x        = (const float*)d_in[0];
    const int*   conn_idx = (const int*)  d_in[1];
    const float* conn_w   = (const float*)d_in[2];
    const float* W1       = (const float*)d_in[3];
    const float* Wg       = (const float*)d_in[4];
    const float* bg       = (const float*)d_in[5];
    float*       out      = (float*)d_out;

    unsigned short* W2    = (unsigned short*)d_ws;         // 655,360 fp16 (1.31 MB)
    unsigned short* hb    = W2 + OO * KTOT;                // 1,280,000 fp16 (2.56 MB)
    unsigned short* parts = hb + NV * HH;                  // 3 x 2,560,000 fp16 (15.4 MB)

    hipLaunchKernelGGL(prep_kernel, dim3(128 + NV / 32), dim3(256), 0, stream,
                       Wg, x, W1, W2, hb);
    hipLaunchKernelGGL(geo_kernel, dim3(4 * 313), dim3(256), 0, stream,
                       conn_idx, conn_w, W2, hb, out, parts);
    hipLaunchKernelGGL(norm_kernel, dim3(NV / 32), dim3(256), 0, stream,
                       out, parts, bg);
}